// Round 12
// baseline (1854.264 us; speedup 1.0000x reference)
//
#include <hip/hip_runtime.h>
#include <hip/hip_fp16.h>

// ---------------------------------------------------------------------------
// 2-layer GCN (PyG GCNConv): deg^{-1/2} sym norm with self-loops.
// Round 12 = round 11 + degree-sorted wave grouping.
//   - Counting-sort nodes by padded degree (bucket = pdeg/8). Gather waves
//     process perm[] order so the 8 node-groups per wave have ~equal degree
//     -> divergent loop runs ~mean instead of ~max(8) iterations (-30-35%).
//   - Dummy-padded CSR (pad to x8, dummy index N -> zeroed payload row):
//     no masks/ballots in the gather loop.
//   - fdot2 fp32 accumulate; 32-bit offset addressing.
//   - xhT[8][N+1][16] fp16 slices (3.2 MB -> one XCD L2, blockIdx&7 -> XCD).
//   - aggT slice-major [8][N][16]; mgemm1 reads it directly (TIN).
//   - thT [4][N+1][16]; gatherT64 writes row-major out (+b2) directly.
// ---------------------------------------------------------------------------

#define NT 256

typedef _Float16 half8 __attribute__((ext_vector_type(8)));
typedef _Float16 h2 __attribute__((ext_vector_type(2)));
typedef float floatx4 __attribute__((ext_vector_type(4)));

#if __has_builtin(__builtin_amdgcn_fdot2)
__device__ __forceinline__ float dot2f(h2 a, h2 b, float c) {
    return __builtin_amdgcn_fdot2(a, b, c, false);
}
#else
__device__ __forceinline__ float dot2f(h2 a, h2 b, float c) {
    return c + (float)a.x * (float)b.x + (float)a.y * (float)b.y;
}
#endif

// ---------------- init: zero counts + hist, fill srcs with dummy ----------
__global__ void init_k(int* __restrict__ cnt, int* __restrict__ hist,
                       int* __restrict__ srcs, int n, int m) {
    int i = blockIdx.x * NT + threadIdx.x;
    if (i < n) cnt[i] = 0;
    if (i < 128) hist[i] = 0;
    if (i < m) srcs[i] = n;  // dummy index -> zeroed payload row
}

__global__ void deg_count_k(const int* __restrict__ dst, int* __restrict__ c, int e) {
    int i = blockIdx.x * NT + threadIdx.x;
    if (i < e) atomicAdd(&c[dst[i]], 1);
}

// exclusive scan of PADDED counts -> rowptr; emits dinv, pdeg
__global__ void scan1_k(const int* __restrict__ counts, int* __restrict__ rowptr,
                        int* __restrict__ bsum, float* __restrict__ dinv,
                        int* __restrict__ pdeg, int n) {
    __shared__ int s[NT];
    int tid = threadIdx.x, i = blockIdx.x * NT + tid;
    int v = (i < n) ? counts[i] : 0;
    int pv = (v + 7) & ~7;
    if (i < n) {
        dinv[i] = rsqrtf((float)(v + 1));  // +1 self-loop
        pdeg[i] = pv;
    }
    s[tid] = pv;
    __syncthreads();
    for (int off = 1; off < NT; off <<= 1) {
        int t = (tid >= off) ? s[tid - off] : 0;
        __syncthreads();
        if (tid >= off) s[tid] += t;
        __syncthreads();
    }
    if (i < n) rowptr[i] = s[tid] - pv;
    if (tid == NT - 1) bsum[blockIdx.x] = s[tid];
}

__global__ void scan2_k(int* __restrict__ bsum, int nb) {
    __shared__ int s[512];
    __shared__ int carry;
    int tid = threadIdx.x;
    if (tid == 0) carry = 0;
    __syncthreads();
    for (int base = 0; base < nb; base += 512) {
        int i = base + tid;
        int v = (i < nb) ? bsum[i] : 0;
        s[tid] = v;
        __syncthreads();
        for (int off = 1; off < 512; off <<= 1) {
            int t = (tid >= off) ? s[tid - off] : 0;
            __syncthreads();
            if (tid >= off) s[tid] += t;
            __syncthreads();
        }
        int tot = s[511];
        if (i < nb) bsum[i] = s[tid] - v + carry;
        __syncthreads();
        if (tid == 0) carry += tot;
        __syncthreads();
    }
}

__global__ void scan3_k(int* __restrict__ rowptr, const int* __restrict__ bsum,
                        int* __restrict__ cursor, int n) {
    int i = blockIdx.x * NT + threadIdx.x;
    if (i < n) {
        int r = rowptr[i] + bsum[i / NT];
        rowptr[i] = r;
        cursor[i] = r;
    }
}

// ---------------- degree counting-sort (bucket = pdeg/8, 128 buckets) ------
__global__ void hist_k(const int* __restrict__ pdeg, int* __restrict__ hist, int n) {
    int i = blockIdx.x * NT + threadIdx.x;
    if (i < n) atomicAdd(&hist[min(pdeg[i] >> 3, 127)], 1);
}

__global__ void hscan_k(int* __restrict__ hist, int* __restrict__ hcur) {
    __shared__ int s[128];
    int t = threadIdx.x;  // 128 threads
    int v = hist[t];
    s[t] = v;
    __syncthreads();
    for (int off = 1; off < 128; off <<= 1) {
        int x = (t >= off) ? s[t - off] : 0;
        __syncthreads();
        if (t >= off) s[t] += x;
        __syncthreads();
    }
    hcur[t] = s[t] - v;  // exclusive
}

__global__ void psort_k(const int* __restrict__ pdeg, int* __restrict__ hcur,
                        int* __restrict__ perm, int n) {
    int i = blockIdx.x * NT + threadIdx.x;
    if (i < n) {
        int k = min(pdeg[i] >> 3, 127);
        perm[atomicAdd(&hcur[k], 1)] = i;
    }
}

// XCD-localized scatter (round 5)
__global__ __launch_bounds__(NT) void scatter_xcd_k(
    const int* __restrict__ src, const int* __restrict__ dst,
    int* __restrict__ cursor, int* __restrict__ srcs,
    int e, int rpx, int csz) {
    int q  = blockIdx.x & 7;
    int ch = blockIdx.x >> 3;
    int lo = q * rpx, hi = lo + rpx;
    int e0 = ch * csz;
    int e1 = min(e, e0 + csz);
    for (int i = e0 + (int)threadIdx.x; i < e1; i += NT) {
        int d = dst[i];
        if (d >= lo && d < hi) {
            int pos = atomicAdd(&cursor[d], 1);
            srcs[pos] = src[i];
        }
    }
}

// ---------------- conv1T: x -> xhT[8][N+1][16] fp16 (row N zeroed) ---------
__global__ void conv1T_k(const float* __restrict__ x, const float* __restrict__ dinv,
                         __half* __restrict__ xhT, int n) {
    int t = blockIdx.x * NT + threadIdx.x;
    int node = t >> 3;
    if (node > n) return;
    int q = t & 7;
    int4 o0, o1;
    if (node == n) {
        o0 = make_int4(0, 0, 0, 0);
        o1 = o0;
    } else {
        float dn = dinv[node];
        const float4* xp =
            reinterpret_cast<const float4*>(x + (size_t)node * 128 + q * 16);
        __half2 h[8];
#pragma unroll
        for (int j = 0; j < 4; ++j) {
            float4 a = xp[j];
            h[2 * j + 0] = __floats2half2_rn(a.x * dn, a.y * dn);
            h[2 * j + 1] = __floats2half2_rn(a.z * dn, a.w * dn);
        }
        o0 = reinterpret_cast<int4*>(h)[0];
        o1 = reinterpret_cast<int4*>(h)[1];
    }
    int4* op = reinterpret_cast<int4*>(xhT + ((size_t)q * (n + 1) + node) * 16);
    op[0] = o0;
    op[1] = o1;
}

// zero thT's dummy rows; run after mgemm1 (overlays aggT), before mgemm2
__global__ void zero_thT_k(__half* __restrict__ thT, int n) {
    int t = threadIdx.x;  // 64 threads
    int sl = t >> 4, j = t & 15;
    thT[((size_t)sl * (n + 1) + n) * 16 + j] = __float2half(0.0f);
}

// ---------------- sliced gathers, 8 nodes x 8 lanes per wave ----------------
// Payload: [slice][N+1][16] fp16 -> 32 B per node per slice; row N is zeros.
// Nodes taken in degree-sorted perm order -> near-uniform loop per wave.

__global__ __launch_bounds__(NT) void gatherT128_k(
    const int* __restrict__ rowptr, const int* __restrict__ pdeg,
    const int* __restrict__ perm, const int* __restrict__ srcs,
    const float* __restrict__ dinv, const __half* __restrict__ xhT,
    __half2* __restrict__ aggT, int n) {
    const int slice = blockIdx.x & 7;
    const int chunk = blockIdx.x >> 3;
    const int lane  = threadIdx.x & 63;
    const int wid   = threadIdx.x >> 6;
    const int g     = lane >> 3;   // node sub-group 0..7
    const int c     = lane & 7;    // half2 col within slice / srcs sub-index
    const int idx   = chunk * 32 + wid * 8 + g;
    if (idx >= n) return;  // shfl sources stay within each 8-lane group
    const int node = perm[idx];

    const int e0 = rowptr[node];
    const int pd = pdeg[node];
    const char* base = (const char*)(xhT + (size_t)slice * (n + 1) * 16);
    const unsigned c4 = (unsigned)c * 4u;
    const h2 b10 = {(_Float16)1.0f, (_Float16)0.0f};
    const h2 b01 = {(_Float16)0.0f, (_Float16)1.0f};

    // self-loop
    h2 fs = *(const h2*)(base + (size_t)node * 32 + c4);
    float ax = dot2f(fs, b10, 0.0f);
    float ay = dot2f(fs, b01, 0.0f);

    int sidx = srcs[e0 + c];
    for (int jb = 0; jb < pd; jb += 8) {
        int snext = srcs[e0 + jb + 8 + c];  // unconditional: buffer padded
#pragma unroll
        for (int u = 0; u < 8; ++u) {
            int s = __shfl(sidx, (g << 3) | u, 64);
            h2 f = *(const h2*)(base + (unsigned)s * 32u + c4);
            ax = dot2f(f, b10, ax);
            ay = dot2f(f, b01, ay);
        }
        sidx = snext;
    }

    float dn = dinv[node];
    aggT[((size_t)slice * n + node) * 8 + c] = __floats2half2_rn(ax * dn, ay * dn);
}

// gatherT64: 4 slices of 16 cols; q8 -> (slice = q8>>1, node-half = q8&1).
// Writes row-major fp32 out directly (+b2): slice = one 64B line per row.
__global__ __launch_bounds__(NT) void gatherT64_k(
    const int* __restrict__ rowptr, const int* __restrict__ pdeg,
    const int* __restrict__ perm, const int* __restrict__ srcs,
    const float* __restrict__ dinv, const __half* __restrict__ thT,
    const float* __restrict__ b2, float* __restrict__ out, int n) {
    const int q8    = blockIdx.x & 7;
    const int slice = q8 >> 1;
    const int chunk = blockIdx.x >> 3;
    const int lane  = threadIdx.x & 63;
    const int wid   = threadIdx.x >> 6;
    const int g     = lane >> 3;
    const int c     = lane & 7;
    const int idx   = chunk * 64 + (q8 & 1) * 32 + wid * 8 + g;
    if (idx >= n) return;
    const int node = perm[idx];

    const int e0 = rowptr[node];
    const int pd = pdeg[node];
    const char* base = (const char*)(thT + (size_t)slice * (n + 1) * 16);
    const unsigned c4 = (unsigned)c * 4u;
    const h2 b10 = {(_Float16)1.0f, (_Float16)0.0f};
    const h2 b01 = {(_Float16)0.0f, (_Float16)1.0f};

    h2 fs = *(const h2*)(base + (size_t)node * 32 + c4);
    float ax = dot2f(fs, b10, 0.0f);
    float ay = dot2f(fs, b01, 0.0f);

    int sidx = srcs[e0 + c];
    for (int jb = 0; jb < pd; jb += 8) {
        int snext = srcs[e0 + jb + 8 + c];
#pragma unroll
        for (int u = 0; u < 8; ++u) {
            int s = __shfl(sidx, (g << 3) | u, 64);
            h2 f = *(const h2*)(base + (unsigned)s * 32u + c4);
            ax = dot2f(f, b10, ax);
            ay = dot2f(f, b01, ay);
        }
        sidx = snext;
    }

    float dn = dinv[node];
    int col = slice * 16 + c * 2;
    *reinterpret_cast<float2*>(&out[(size_t)node * 64 + col]) =
        make_float2(ax * dn + b2[col], ay * dn + b2[col + 1]);
}

// ---------------- MFMA fp16 GEMM, register-resident B ----------------
// TIN=true : A is slice-major [8][nrows][16] fp16 (aggT, stride nrows).
// TOUT=true: out slice-major [OC/16][orows][16] fp16 (thT, stride orows).
template <int OC, bool RELU, bool BIAS, bool SCALE_DINV, bool TIN, bool TOUT>
__global__ __launch_bounds__(NT) void mgemm_k(
    const __half* __restrict__ A, const float* __restrict__ W,
    const float* __restrict__ bias, const float* __restrict__ dinv,
    __half* __restrict__ out, int nrows, int orows) {
    constexpr int NREP = OC / 64;  // 2 for OC=128, 1 for OC=64

    const int wid  = threadIdx.x >> 6;
    const int lane = threadIdx.x & 63;
    const int lrow = lane & 15;
    const int kgrp = lane >> 4;
    const int nbase = wid * 16 * NREP;

    // B fragments (loaded once, stay in VGPRs)
    half8 bf[NREP][4];
    float bv[NREP];
#pragma unroll
    for (int nt = 0; nt < NREP; ++nt) {
        int col = nbase + nt * 16 + lrow;
#pragma unroll
        for (int kk = 0; kk < 4; ++kk) {
#pragma unroll
            for (int j = 0; j < 8; ++j) {
                int k = kk * 32 + kgrp * 8 + j;
                bf[nt][kk][j] = (_Float16)W[(size_t)k * OC + col];
            }
        }
        bv[nt] = BIAS ? bias[col] : 0.0f;
    }

    const int m0 = blockIdx.x * 64;

    floatx4 acc[4][NREP];
#pragma unroll
    for (int mt = 0; mt < 4; ++mt)
#pragma unroll
        for (int nt = 0; nt < NREP; ++nt)
            acc[mt][nt] = floatx4{0.f, 0.f, 0.f, 0.f};

#pragma unroll
    for (int kk = 0; kk < 4; ++kk) {
        const int k0 = kk * 32 + kgrp * 8;
        half8 af[4];
#pragma unroll
        for (int mt = 0; mt < 4; ++mt) {
            int row = m0 + mt * 16 + lrow;
            if (row >= nrows) row = nrows - 1;  // clamp; stores guarded
            af[mt] = TIN
                ? *reinterpret_cast<const half8*>(
                      &A[(((size_t)(k0 >> 4)) * nrows + row) * 16 + (k0 & 15)])
                : *reinterpret_cast<const half8*>(&A[(size_t)row * 128 + k0]);
        }
#pragma unroll
        for (int mt = 0; mt < 4; ++mt)
#pragma unroll
            for (int nt = 0; nt < NREP; ++nt)
                acc[mt][nt] = __builtin_amdgcn_mfma_f32_16x16x32_f16(
                    af[mt], bf[nt][kk], acc[mt][nt], 0, 0, 0);
    }

#pragma unroll
    for (int mt = 0; mt < 4; ++mt) {
#pragma unroll
        for (int r = 0; r < 4; ++r) {
            int row = m0 + mt * 16 + kgrp * 4 + r;
            if (row < nrows) {
                float dn = SCALE_DINV ? dinv[row] : 1.0f;
#pragma unroll
                for (int nt = 0; nt < NREP; ++nt) {
                    float v = acc[mt][nt][r];
                    if (BIAS) v += bv[nt];
                    if (RELU) v = fmaxf(v, 0.0f);
                    if (SCALE_DINV) v *= dn;
                    int col = nbase + nt * 16 + lrow;
                    if (TOUT)
                        out[((size_t)(col >> 4) * orows + row) * 16 + (col & 15)] =
                            __float2half(v);
                    else
                        out[(size_t)row * OC + col] = __float2half(v);
                }
            }
        }
    }
}

// ---------------------------------------------------------------------------

extern "C" void kernel_launch(void* const* d_in, const int* in_sizes, int n_in,
                              void* d_out, int out_size, void* d_ws, size_t ws_size,
                              hipStream_t stream) {
    const float* x   = (const float*)d_in[0];
    const int*   ei  = (const int*)d_in[1];
    const float* W1  = (const float*)d_in[2];
    const float* b1  = (const float*)d_in[3];
    const float* W2  = (const float*)d_in[4];
    const float* b2  = (const float*)d_in[5];
    float*       out = (float*)d_out;

    const int N = in_sizes[0] / 128;
    const int E = in_sizes[1] / 2;
    const int* srcp = ei;      // edge_index[0]
    const int* dstp = ei + E;  // edge_index[1]

    const int nb   = (N + NT - 1) / NT;
    const int EPAD = E + 8 * N;  // >= sum(padded degrees) + prefetch slack

    // workspace (512B-aligned):
    //   dinv[N] | cnt[N] | pdeg[N] | rowptr[N] | bsum[nb] | hist[128] |
    //   hcur[128] | perm[N] | srcs[EPAD]
    //   | regA: xhT[8][N+1][16] fp16, then h1[N][128] fp16
    //   | regB: aggT[8][N][16] fp16, then thT[4][N+1][16] fp16
    char* ws = (char*)d_ws;
    size_t off = 0;
    auto alloc = [&](size_t bytes) {
        char* p = ws + off;
        off = (off + bytes + 511) & ~(size_t)511;
        return p;
    };
    float*  dinv   = (float*)alloc((size_t)N * 4);
    int*    cnt    = (int*)alloc((size_t)N * 4);   // counts, then scatter cursor
    int*    pdeg   = (int*)alloc((size_t)N * 4);
    int*    rowptr = (int*)alloc((size_t)N * 4);
    int*    bsum   = (int*)alloc((size_t)nb * 4);
    int*    hist   = (int*)alloc(128 * 4);
    int*    hcur   = (int*)alloc(128 * 4);
    int*    perm   = (int*)alloc((size_t)N * 4);
    int*    srcs   = (int*)alloc((size_t)EPAD * 4);
    __half* regA   = (__half*)alloc((size_t)(N + 1) * 128 * 2);
    __half* regB   = (__half*)alloc((size_t)(N + 1) * 128 * 2);

    // ---- padded CSR build + norm + degree sort ----
    const int mi = (EPAD > N) ? EPAD : N;
    init_k<<<(mi + NT - 1) / NT, NT, 0, stream>>>(cnt, hist, srcs, N, EPAD);
    deg_count_k<<<(E + NT - 1) / NT, NT, 0, stream>>>(dstp, cnt, E);
    scan1_k<<<nb, NT, 0, stream>>>(cnt, rowptr, bsum, dinv, pdeg, N);
    scan2_k<<<1, 512, 0, stream>>>(bsum, nb);
    scan3_k<<<nb, NT, 0, stream>>>(rowptr, bsum, cnt, N);
    hist_k<<<nb, NT, 0, stream>>>(pdeg, hist, N);
    hscan_k<<<1, 128, 0, stream>>>(hist, hcur);
    psort_k<<<nb, NT, 0, stream>>>(pdeg, hcur, perm, N);
    {
        const int CH  = 2048;
        const int csz = (E + CH - 1) / CH;
        const int rpx = (N + 7) / 8;
        scatter_xcd_k<<<8 * CH, NT, 0, stream>>>(srcp, dstp, cnt, srcs, E, rpx, csz);
    }

    // ---- layer 1: xhT (padded, dummy row zeroed) -> aggT -> h1 ----
    conv1T_k<<<((N + 1) * 8 + NT - 1) / NT, NT, 0, stream>>>(x, dinv, regA, N);
    gatherT128_k<<<((N + 31) / 32) * 8, NT, 0, stream>>>(
        rowptr, pdeg, perm, srcs, dinv, regA, (__half2*)regB, N);
    __half* h1 = regA;  // overlays xhT (dead)
    mgemm_k<128, true, true, false, true, false><<<(N + 63) / 64, NT, 0, stream>>>(
        regB, W1, b1, nullptr, h1, N, N);

    // ---- layer 2: thT = (h1 @ W2)*dinv (slice-major, padded) -> out ----
    __half* thT = regB;  // overlays aggT (dead)
    zero_thT_k<<<1, 64, 0, stream>>>(thT, N);
    mgemm_k<64, false, false, true, false, true><<<(N + 63) / 64, NT, 0, stream>>>(
        h1, W2, nullptr, dinv, thT, N, N + 1);
    gatherT64_k<<<((N + 63) / 64) * 8, NT, 0, stream>>>(
        rowptr, pdeg, perm, srcs, dinv, thT, b2, out, N);
}

// Round 13
// 353.793 us; speedup vs baseline: 5.2411x; 5.2411x over previous
//
#include <hip/hip_runtime.h>
#include <hip/hip_fp16.h>

// ---------------------------------------------------------------------------
// 2-layer GCN (PyG GCNConv): deg^{-1/2} sym norm with self-loops.
// Round 13 = round 12 with the counting-sort atomics fixed (LDS-first
// two-level histograms; round 12's global same-address atomics were 1.5 ms).
//   - Degree-sorted wave grouping: gather waves process perm[] so the 8
//     node-groups per wave have ~equal degree (loop ~mean, not ~max-of-8).
//   - Dummy-padded CSR (pad to x8, dummy index N -> zeroed payload row):
//     no masks/ballots in the gather loop; fdot2 fp32 accumulate.
//   - xhT[8][N+1][16] fp16 slices (3.2 MB -> one XCD L2, blockIdx&7 -> XCD).
//   - aggT slice-major [8][N][16]; mgemm1 reads it directly (TIN).
//   - thT [4][N+1][16]; gatherT64 writes row-major out (+b2) directly.
// ---------------------------------------------------------------------------

#define NT 256

typedef _Float16 half8 __attribute__((ext_vector_type(8)));
typedef _Float16 h2 __attribute__((ext_vector_type(2)));
typedef float floatx4 __attribute__((ext_vector_type(4)));

#if __has_builtin(__builtin_amdgcn_fdot2)
__device__ __forceinline__ float dot2f(h2 a, h2 b, float c) {
    return __builtin_amdgcn_fdot2(a, b, c, false);
}
#else
__device__ __forceinline__ float dot2f(h2 a, h2 b, float c) {
    return c + (float)a.x * (float)b.x + (float)a.y * (float)b.y;
}
#endif

// ---------------- init: zero counts + hist, fill srcs with dummy ----------
__global__ void init_k(int* __restrict__ cnt, int* __restrict__ hist,
                       int* __restrict__ srcs, int n, int m) {
    int i = blockIdx.x * NT + threadIdx.x;
    if (i < n) cnt[i] = 0;
    if (i < 128) hist[i] = 0;
    if (i < m) srcs[i] = n;  // dummy index -> zeroed payload row
}

__global__ void deg_count_k(const int* __restrict__ dst, int* __restrict__ c, int e) {
    int i = blockIdx.x * NT + threadIdx.x;
    if (i < e) atomicAdd(&c[dst[i]], 1);
}

// exclusive scan of PADDED counts -> rowptr; emits dinv, pdeg
__global__ void scan1_k(const int* __restrict__ counts, int* __restrict__ rowptr,
                        int* __restrict__ bsum, float* __restrict__ dinv,
                        int* __restrict__ pdeg, int n) {
    __shared__ int s[NT];
    int tid = threadIdx.x, i = blockIdx.x * NT + tid;
    int v = (i < n) ? counts[i] : 0;
    int pv = (v + 7) & ~7;
    if (i < n) {
        dinv[i] = rsqrtf((float)(v + 1));  // +1 self-loop
        pdeg[i] = pv;
    }
    s[tid] = pv;
    __syncthreads();
    for (int off = 1; off < NT; off <<= 1) {
        int t = (tid >= off) ? s[tid - off] : 0;
        __syncthreads();
        if (tid >= off) s[tid] += t;
        __syncthreads();
    }
    if (i < n) rowptr[i] = s[tid] - pv;
    if (tid == NT - 1) bsum[blockIdx.x] = s[tid];
}

__global__ void scan2_k(int* __restrict__ bsum, int nb) {
    __shared__ int s[512];
    __shared__ int carry;
    int tid = threadIdx.x;
    if (tid == 0) carry = 0;
    __syncthreads();
    for (int base = 0; base < nb; base += 512) {
        int i = base + tid;
        int v = (i < nb) ? bsum[i] : 0;
        s[tid] = v;
        __syncthreads();
        for (int off = 1; off < 512; off <<= 1) {
            int t = (tid >= off) ? s[tid - off] : 0;
            __syncthreads();
            if (tid >= off) s[tid] += t;
            __syncthreads();
        }
        int tot = s[511];
        if (i < nb) bsum[i] = s[tid] - v + carry;
        __syncthreads();
        if (tid == 0) carry += tot;
        __syncthreads();
    }
}

__global__ void scan3_k(int* __restrict__ rowptr, const int* __restrict__ bsum,
                        int* __restrict__ cursor, int n) {
    int i = blockIdx.x * NT + threadIdx.x;
    if (i < n) {
        int r = rowptr[i] + bsum[i / NT];
        rowptr[i] = r;
        cursor[i] = r;
    }
}

// ---------------- degree counting-sort (bucket = pdeg/8, 128 buckets) ------
// LDS-first histograms: per-block LDS atomics, then <=128 global atomics per
// block (round 12's 100k same-address GLOBAL atomics cost 1.5 ms).

__global__ void hist_k(const int* __restrict__ pdeg, int* __restrict__ hist, int n) {
    __shared__ int lh[128];
    int tid = threadIdx.x;
    if (tid < 128) lh[tid] = 0;
    __syncthreads();
    int i = blockIdx.x * NT + tid;
    if (i < n) atomicAdd(&lh[min(pdeg[i] >> 3, 127)], 1);
    __syncthreads();
    if (tid < 128 && lh[tid] > 0) atomicAdd(&hist[tid], lh[tid]);
}

__global__ void hscan_k(int* __restrict__ hist, int* __restrict__ hcur) {
    __shared__ int s[128];
    int t = threadIdx.x;  // 128 threads
    int v = hist[t];
    s[t] = v;
    __syncthreads();
    for (int off = 1; off < 128; off <<= 1) {
        int x = (t >= off) ? s[t - off] : 0;
        __syncthreads();
        if (t >= off) s[t] += x;
        __syncthreads();
    }
    hcur[t] = s[t] - v;  // exclusive
}

// two-level scatter: LDS rank within block, one global atomicAdd per
// (block, bucket) to reserve the output range. perm ordering is run-varying
// but output values are invariant (perm only re-assigns nodes to waves).
__global__ void psort_k(const int* __restrict__ pdeg, int* __restrict__ hcur,
                        int* __restrict__ perm, int n) {
    __shared__ int lh[128];
    __shared__ int lbase[128];
    int tid = threadIdx.x;
    int i = blockIdx.x * NT + tid;
    if (tid < 128) lh[tid] = 0;
    __syncthreads();
    int k = 0, lr = 0;
    bool v = i < n;
    if (v) {
        k = min(pdeg[i] >> 3, 127);
        lr = atomicAdd(&lh[k], 1);  // LDS atomic: cheap
    }
    __syncthreads();
    if (tid < 128 && lh[tid] > 0)
        lbase[tid] = atomicAdd(&hcur[tid], lh[tid]);  // <=128 global/block
    __syncthreads();
    if (v) perm[lbase[k] + lr] = i;
}

// XCD-localized scatter (round 5)
__global__ __launch_bounds__(NT) void scatter_xcd_k(
    const int* __restrict__ src, const int* __restrict__ dst,
    int* __restrict__ cursor, int* __restrict__ srcs,
    int e, int rpx, int csz) {
    int q  = blockIdx.x & 7;
    int ch = blockIdx.x >> 3;
    int lo = q * rpx, hi = lo + rpx;
    int e0 = ch * csz;
    int e1 = min(e, e0 + csz);
    for (int i = e0 + (int)threadIdx.x; i < e1; i += NT) {
        int d = dst[i];
        if (d >= lo && d < hi) {
            int pos = atomicAdd(&cursor[d], 1);
            srcs[pos] = src[i];
        }
    }
}

// ---------------- conv1T: x -> xhT[8][N+1][16] fp16 (row N zeroed) ---------
__global__ void conv1T_k(const float* __restrict__ x, const float* __restrict__ dinv,
                         __half* __restrict__ xhT, int n) {
    int t = blockIdx.x * NT + threadIdx.x;
    int node = t >> 3;
    if (node > n) return;
    int q = t & 7;
    int4 o0, o1;
    if (node == n) {
        o0 = make_int4(0, 0, 0, 0);
        o1 = o0;
    } else {
        float dn = dinv[node];
        const float4* xp =
            reinterpret_cast<const float4*>(x + (size_t)node * 128 + q * 16);
        __half2 h[8];
#pragma unroll
        for (int j = 0; j < 4; ++j) {
            float4 a = xp[j];
            h[2 * j + 0] = __floats2half2_rn(a.x * dn, a.y * dn);
            h[2 * j + 1] = __floats2half2_rn(a.z * dn, a.w * dn);
        }
        o0 = reinterpret_cast<int4*>(h)[0];
        o1 = reinterpret_cast<int4*>(h)[1];
    }
    int4* op = reinterpret_cast<int4*>(xhT + ((size_t)q * (n + 1) + node) * 16);
    op[0] = o0;
    op[1] = o1;
}

// zero thT's dummy rows; run after mgemm1 (overlays aggT), before mgemm2
__global__ void zero_thT_k(__half* __restrict__ thT, int n) {
    int t = threadIdx.x;  // 64 threads
    int sl = t >> 4, j = t & 15;
    thT[((size_t)sl * (n + 1) + n) * 16 + j] = __float2half(0.0f);
}

// ---------------- sliced gathers, 8 nodes x 8 lanes per wave ----------------
// Payload: [slice][N+1][16] fp16 -> 32 B per node per slice; row N is zeros.
// Nodes taken in degree-sorted perm order -> near-uniform loop per wave.

__global__ __launch_bounds__(NT) void gatherT128_k(
    const int* __restrict__ rowptr, const int* __restrict__ pdeg,
    const int* __restrict__ perm, const int* __restrict__ srcs,
    const float* __restrict__ dinv, const __half* __restrict__ xhT,
    __half2* __restrict__ aggT, int n) {
    const int slice = blockIdx.x & 7;
    const int chunk = blockIdx.x >> 3;
    const int lane  = threadIdx.x & 63;
    const int wid   = threadIdx.x >> 6;
    const int g     = lane >> 3;   // node sub-group 0..7
    const int c     = lane & 7;    // half2 col within slice / srcs sub-index
    const int idx   = chunk * 32 + wid * 8 + g;
    if (idx >= n) return;  // shfl sources stay within each 8-lane group
    const int node = perm[idx];

    const int e0 = rowptr[node];
    const int pd = pdeg[node];
    const char* base = (const char*)(xhT + (size_t)slice * (n + 1) * 16);
    const unsigned c4 = (unsigned)c * 4u;
    const h2 b10 = {(_Float16)1.0f, (_Float16)0.0f};
    const h2 b01 = {(_Float16)0.0f, (_Float16)1.0f};

    // self-loop
    h2 fs = *(const h2*)(base + (size_t)node * 32 + c4);
    float ax = dot2f(fs, b10, 0.0f);
    float ay = dot2f(fs, b01, 0.0f);

    int sidx = srcs[e0 + c];
    for (int jb = 0; jb < pd; jb += 8) {
        int snext = srcs[e0 + jb + 8 + c];  // unconditional: buffer padded
#pragma unroll
        for (int u = 0; u < 8; ++u) {
            int s = __shfl(sidx, (g << 3) | u, 64);
            h2 f = *(const h2*)(base + (unsigned)s * 32u + c4);
            ax = dot2f(f, b10, ax);
            ay = dot2f(f, b01, ay);
        }
        sidx = snext;
    }

    float dn = dinv[node];
    aggT[((size_t)slice * n + node) * 8 + c] = __floats2half2_rn(ax * dn, ay * dn);
}

// gatherT64: 4 slices of 16 cols; q8 -> (slice = q8>>1, node-half = q8&1).
// Writes row-major fp32 out directly (+b2): slice = one 64B line per row.
__global__ __launch_bounds__(NT) void gatherT64_k(
    const int* __restrict__ rowptr, const int* __restrict__ pdeg,
    const int* __restrict__ perm, const int* __restrict__ srcs,
    const float* __restrict__ dinv, const __half* __restrict__ thT,
    const float* __restrict__ b2, float* __restrict__ out, int n) {
    const int q8    = blockIdx.x & 7;
    const int slice = q8 >> 1;
    const int chunk = blockIdx.x >> 3;
    const int lane  = threadIdx.x & 63;
    const int wid   = threadIdx.x >> 6;
    const int g     = lane >> 3;
    const int c     = lane & 7;
    const int idx   = chunk * 64 + (q8 & 1) * 32 + wid * 8 + g;
    if (idx >= n) return;
    const int node = perm[idx];

    const int e0 = rowptr[node];
    const int pd = pdeg[node];
    const char* base = (const char*)(thT + (size_t)slice * (n + 1) * 16);
    const unsigned c4 = (unsigned)c * 4u;
    const h2 b10 = {(_Float16)1.0f, (_Float16)0.0f};
    const h2 b01 = {(_Float16)0.0f, (_Float16)1.0f};

    h2 fs = *(const h2*)(base + (size_t)node * 32 + c4);
    float ax = dot2f(fs, b10, 0.0f);
    float ay = dot2f(fs, b01, 0.0f);

    int sidx = srcs[e0 + c];
    for (int jb = 0; jb < pd; jb += 8) {
        int snext = srcs[e0 + jb + 8 + c];
#pragma unroll
        for (int u = 0; u < 8; ++u) {
            int s = __shfl(sidx, (g << 3) | u, 64);
            h2 f = *(const h2*)(base + (unsigned)s * 32u + c4);
            ax = dot2f(f, b10, ax);
            ay = dot2f(f, b01, ay);
        }
        sidx = snext;
    }

    float dn = dinv[node];
    int col = slice * 16 + c * 2;
    *reinterpret_cast<float2*>(&out[(size_t)node * 64 + col]) =
        make_float2(ax * dn + b2[col], ay * dn + b2[col + 1]);
}

// ---------------- MFMA fp16 GEMM, register-resident B ----------------
// TIN=true : A is slice-major [8][nrows][16] fp16 (aggT, stride nrows).
// TOUT=true: out slice-major [OC/16][orows][16] fp16 (thT, stride orows).
template <int OC, bool RELU, bool BIAS, bool SCALE_DINV, bool TIN, bool TOUT>
__global__ __launch_bounds__(NT) void mgemm_k(
    const __half* __restrict__ A, const float* __restrict__ W,
    const float* __restrict__ bias, const float* __restrict__ dinv,
    __half* __restrict__ out, int nrows, int orows) {
    constexpr int NREP = OC / 64;  // 2 for OC=128, 1 for OC=64

    const int wid  = threadIdx.x >> 6;
    const int lane = threadIdx.x & 63;
    const int lrow = lane & 15;
    const int kgrp = lane >> 4;
    const int nbase = wid * 16 * NREP;

    // B fragments (loaded once, stay in VGPRs)
    half8 bf[NREP][4];
    float bv[NREP];
#pragma unroll
    for (int nt = 0; nt < NREP; ++nt) {
        int col = nbase + nt * 16 + lrow;
#pragma unroll
        for (int kk = 0; kk < 4; ++kk) {
#pragma unroll
            for (int j = 0; j < 8; ++j) {
                int k = kk * 32 + kgrp * 8 + j;
                bf[nt][kk][j] = (_Float16)W[(size_t)k * OC + col];
            }
        }
        bv[nt] = BIAS ? bias[col] : 0.0f;
    }

    const int m0 = blockIdx.x * 64;

    floatx4 acc[4][NREP];
#pragma unroll
    for (int mt = 0; mt < 4; ++mt)
#pragma unroll
        for (int nt = 0; nt < NREP; ++nt)
            acc[mt][nt] = floatx4{0.f, 0.f, 0.f, 0.f};

#pragma unroll
    for (int kk = 0; kk < 4; ++kk) {
        const int k0 = kk * 32 + kgrp * 8;
        half8 af[4];
#pragma unroll
        for (int mt = 0; mt < 4; ++mt) {
            int row = m0 + mt * 16 + lrow;
            if (row >= nrows) row = nrows - 1;  // clamp; stores guarded
            af[mt] = TIN
                ? *reinterpret_cast<const half8*>(
                      &A[(((size_t)(k0 >> 4)) * nrows + row) * 16 + (k0 & 15)])
                : *reinterpret_cast<const half8*>(&A[(size_t)row * 128 + k0]);
        }
#pragma unroll
        for (int mt = 0; mt < 4; ++mt)
#pragma unroll
            for (int nt = 0; nt < NREP; ++nt)
                acc[mt][nt] = __builtin_amdgcn_mfma_f32_16x16x32_f16(
                    af[mt], bf[nt][kk], acc[mt][nt], 0, 0, 0);
    }

#pragma unroll
    for (int mt = 0; mt < 4; ++mt) {
#pragma unroll
        for (int r = 0; r < 4; ++r) {
            int row = m0 + mt * 16 + kgrp * 4 + r;
            if (row < nrows) {
                float dn = SCALE_DINV ? dinv[row] : 1.0f;
#pragma unroll
                for (int nt = 0; nt < NREP; ++nt) {
                    float v = acc[mt][nt][r];
                    if (BIAS) v += bv[nt];
                    if (RELU) v = fmaxf(v, 0.0f);
                    if (SCALE_DINV) v *= dn;
                    int col = nbase + nt * 16 + lrow;
                    if (TOUT)
                        out[((size_t)(col >> 4) * orows + row) * 16 + (col & 15)] =
                            __float2half(v);
                    else
                        out[(size_t)row * OC + col] = __float2half(v);
                }
            }
        }
    }
}

// ---------------------------------------------------------------------------

extern "C" void kernel_launch(void* const* d_in, const int* in_sizes, int n_in,
                              void* d_out, int out_size, void* d_ws, size_t ws_size,
                              hipStream_t stream) {
    const float* x   = (const float*)d_in[0];
    const int*   ei  = (const int*)d_in[1];
    const float* W1  = (const float*)d_in[2];
    const float* b1  = (const float*)d_in[3];
    const float* W2  = (const float*)d_in[4];
    const float* b2  = (const float*)d_in[5];
    float*       out = (float*)d_out;

    const int N = in_sizes[0] / 128;
    const int E = in_sizes[1] / 2;
    const int* srcp = ei;      // edge_index[0]
    const int* dstp = ei + E;  // edge_index[1]

    const int nb   = (N + NT - 1) / NT;
    const int EPAD = E + 8 * N;  // >= sum(padded degrees) + prefetch slack

    // workspace (512B-aligned):
    //   dinv[N] | cnt[N] | pdeg[N] | rowptr[N] | bsum[nb] | hist[128] |
    //   hcur[128] | perm[N] | srcs[EPAD]
    //   | regA: xhT[8][N+1][16] fp16, then h1[N][128] fp16
    //   | regB: aggT[8][N][16] fp16, then thT[4][N+1][16] fp16
    char* ws = (char*)d_ws;
    size_t off = 0;
    auto alloc = [&](size_t bytes) {
        char* p = ws + off;
        off = (off + bytes + 511) & ~(size_t)511;
        return p;
    };
    float*  dinv   = (float*)alloc((size_t)N * 4);
    int*    cnt    = (int*)alloc((size_t)N * 4);   // counts, then scatter cursor
    int*    pdeg   = (int*)alloc((size_t)N * 4);
    int*    rowptr = (int*)alloc((size_t)N * 4);
    int*    bsum   = (int*)alloc((size_t)nb * 4);
    int*    hist   = (int*)alloc(128 * 4);
    int*    hcur   = (int*)alloc(128 * 4);
    int*    perm   = (int*)alloc((size_t)N * 4);
    int*    srcs   = (int*)alloc((size_t)EPAD * 4);
    __half* regA   = (__half*)alloc((size_t)(N + 1) * 128 * 2);
    __half* regB   = (__half*)alloc((size_t)(N + 1) * 128 * 2);

    // ---- padded CSR build + norm + degree sort ----
    const int mi = (EPAD > N) ? EPAD : N;
    init_k<<<(mi + NT - 1) / NT, NT, 0, stream>>>(cnt, hist, srcs, N, EPAD);
    deg_count_k<<<(E + NT - 1) / NT, NT, 0, stream>>>(dstp, cnt, E);
    scan1_k<<<nb, NT, 0, stream>>>(cnt, rowptr, bsum, dinv, pdeg, N);
    scan2_k<<<1, 512, 0, stream>>>(bsum, nb);
    scan3_k<<<nb, NT, 0, stream>>>(rowptr, bsum, cnt, N);
    hist_k<<<nb, NT, 0, stream>>>(pdeg, hist, N);
    hscan_k<<<1, 128, 0, stream>>>(hist, hcur);
    psort_k<<<nb, NT, 0, stream>>>(pdeg, hcur, perm, N);
    {
        const int CH  = 2048;
        const int csz = (E + CH - 1) / CH;
        const int rpx = (N + 7) / 8;
        scatter_xcd_k<<<8 * CH, NT, 0, stream>>>(srcp, dstp, cnt, srcs, E, rpx, csz);
    }

    // ---- layer 1: xhT (padded, dummy row zeroed) -> aggT -> h1 ----
    conv1T_k<<<((N + 1) * 8 + NT - 1) / NT, NT, 0, stream>>>(x, dinv, regA, N);
    gatherT128_k<<<((N + 31) / 32) * 8, NT, 0, stream>>>(
        rowptr, pdeg, perm, srcs, dinv, regA, (__half2*)regB, N);
    __half* h1 = regA;  // overlays xhT (dead)
    mgemm_k<128, true, true, false, true, false><<<(N + 63) / 64, NT, 0, stream>>>(
        regB, W1, b1, nullptr, h1, N, N);

    // ---- layer 2: thT = (h1 @ W2)*dinv (slice-major, padded) -> out ----
    __half* thT = regB;  // overlays aggT (dead)
    zero_thT_k<<<1, 64, 0, stream>>>(thT, N);
    mgemm_k<64, false, false, true, false, true><<<(N + 63) / 64, NT, 0, stream>>>(
        h1, W2, nullptr, dinv, thT, N, N + 1);
    gatherT64_k<<<((N + 63) / 64) * 8, NT, 0, stream>>>(
        rowptr, pdeg, perm, srcs, dinv, thT, b2, out, N);
}

// Round 14
// 329.199 us; speedup vs baseline: 5.6327x; 1.0747x over previous
//
#include <hip/hip_runtime.h>
#include <hip/hip_fp16.h>

// ---------------------------------------------------------------------------
// 2-layer GCN (PyG GCNConv): deg^{-1/2} sym norm with self-loops.
// Round 14 = round 11 + WITHIN-CHUNK degree sort (round 13's GLOBAL sort
// equalized degrees but randomized all memory locality: FETCH 59->131 MB).
//   - csort_k: 32-element bitonic sort per 32-node chunk -> perm[idx] stays
//     inside idx's chunk. Waves get degree-matched node groups (loop ~1.1x
//     mean instead of max-of-8 ~1.45x mean) with UNCHANGED locality.
//   - Dummy-padded CSR (pad to x8, dummy index N -> zeroed payload row):
//     no masks/ballots in the gather loop; fdot2 fp32 accumulate.
//   - xhT[8][N+1][16] fp16 slices (3.2 MB -> one XCD L2, blockIdx&7 -> XCD).
//   - aggT slice-major [8][N][16]; mgemm1 reads it directly (TIN).
//   - thT [4][N+1][16]; gatherT64 writes row-major out (+b2) directly.
// ---------------------------------------------------------------------------

#define NT 256

typedef _Float16 half8 __attribute__((ext_vector_type(8)));
typedef _Float16 h2 __attribute__((ext_vector_type(2)));
typedef float floatx4 __attribute__((ext_vector_type(4)));

#if __has_builtin(__builtin_amdgcn_fdot2)
__device__ __forceinline__ float dot2f(h2 a, h2 b, float c) {
    return __builtin_amdgcn_fdot2(a, b, c, false);
}
#else
__device__ __forceinline__ float dot2f(h2 a, h2 b, float c) {
    return c + (float)a.x * (float)b.x + (float)a.y * (float)b.y;
}
#endif

// ---------------- init: zero counts, fill srcs with dummy ----------
__global__ void init_k(int* __restrict__ cnt, int* __restrict__ srcs, int n, int m) {
    int i = blockIdx.x * NT + threadIdx.x;
    if (i < n) cnt[i] = 0;
    if (i < m) srcs[i] = n;  // dummy index -> zeroed payload row
}

__global__ void deg_count_k(const int* __restrict__ dst, int* __restrict__ c, int e) {
    int i = blockIdx.x * NT + threadIdx.x;
    if (i < e) atomicAdd(&c[dst[i]], 1);
}

// exclusive scan of PADDED counts -> rowptr; emits dinv, pdeg
__global__ void scan1_k(const int* __restrict__ counts, int* __restrict__ rowptr,
                        int* __restrict__ bsum, float* __restrict__ dinv,
                        int* __restrict__ pdeg, int n) {
    __shared__ int s[NT];
    int tid = threadIdx.x, i = blockIdx.x * NT + tid;
    int v = (i < n) ? counts[i] : 0;
    int pv = (v + 7) & ~7;
    if (i < n) {
        dinv[i] = rsqrtf((float)(v + 1));  // +1 self-loop
        pdeg[i] = pv;
    }
    s[tid] = pv;
    __syncthreads();
    for (int off = 1; off < NT; off <<= 1) {
        int t = (tid >= off) ? s[tid - off] : 0;
        __syncthreads();
        if (tid >= off) s[tid] += t;
        __syncthreads();
    }
    if (i < n) rowptr[i] = s[tid] - pv;
    if (tid == NT - 1) bsum[blockIdx.x] = s[tid];
}

__global__ void scan2_k(int* __restrict__ bsum, int nb) {
    __shared__ int s[512];
    __shared__ int carry;
    int tid = threadIdx.x;
    if (tid == 0) carry = 0;
    __syncthreads();
    for (int base = 0; base < nb; base += 512) {
        int i = base + tid;
        int v = (i < nb) ? bsum[i] : 0;
        s[tid] = v;
        __syncthreads();
        for (int off = 1; off < 512; off <<= 1) {
            int t = (tid >= off) ? s[tid - off] : 0;
            __syncthreads();
            if (tid >= off) s[tid] += t;
            __syncthreads();
        }
        int tot = s[511];
        if (i < nb) bsum[i] = s[tid] - v + carry;
        __syncthreads();
        if (tid == 0) carry += tot;
        __syncthreads();
    }
}

__global__ void scan3_k(int* __restrict__ rowptr, const int* __restrict__ bsum,
                        int* __restrict__ cursor, int n) {
    int i = blockIdx.x * NT + threadIdx.x;
    if (i < n) {
        int r = rowptr[i] + bsum[i / NT];
        rowptr[i] = r;
        cursor[i] = r;
    }
}

// ---------------- within-chunk degree sort (32-node chunks) ----------------
// Bitonic sort (ascending by pdeg) of each 32-node chunk; perm[idx] stays
// within idx's own chunk -> gather locality is untouched while the 8-node
// groups of each wave become degree-matched. Tail keys padded w/ INT_MAX so
// valid nodes occupy the low positions.
__global__ void csort_k(const int* __restrict__ pdeg, int* __restrict__ perm, int n) {
    __shared__ int key[NT], val[NT];
    int tid = threadIdx.x;
    int i = blockIdx.x * NT + tid;
    key[tid] = (i < n) ? pdeg[i] : 0x7fffffff;
    val[tid] = i;
    __syncthreads();
    int lid = tid & 31, cb = tid & ~31;
    for (int k = 2; k <= 32; k <<= 1) {
        for (int j = k >> 1; j > 0; j >>= 1) {
            int ixj = lid ^ j;
            if (ixj > lid) {
                bool up = ((lid & k) == 0);
                int ka = key[cb + lid], kb = key[cb + ixj];
                if ((ka > kb) == up) {
                    int va = val[cb + lid], vb = val[cb + ixj];
                    key[cb + lid] = kb; key[cb + ixj] = ka;
                    val[cb + lid] = vb; val[cb + ixj] = va;
                }
            }
            __syncthreads();
        }
    }
    if (i < n) perm[i] = val[tid];
}

// XCD-localized scatter (round 5)
__global__ __launch_bounds__(NT) void scatter_xcd_k(
    const int* __restrict__ src, const int* __restrict__ dst,
    int* __restrict__ cursor, int* __restrict__ srcs,
    int e, int rpx, int csz) {
    int q  = blockIdx.x & 7;
    int ch = blockIdx.x >> 3;
    int lo = q * rpx, hi = lo + rpx;
    int e0 = ch * csz;
    int e1 = min(e, e0 + csz);
    for (int i = e0 + (int)threadIdx.x; i < e1; i += NT) {
        int d = dst[i];
        if (d >= lo && d < hi) {
            int pos = atomicAdd(&cursor[d], 1);
            srcs[pos] = src[i];
        }
    }
}

// ---------------- conv1T: x -> xhT[8][N+1][16] fp16 (row N zeroed) ---------
__global__ void conv1T_k(const float* __restrict__ x, const float* __restrict__ dinv,
                         __half* __restrict__ xhT, int n) {
    int t = blockIdx.x * NT + threadIdx.x;
    int node = t >> 3;
    if (node > n) return;
    int q = t & 7;
    int4 o0, o1;
    if (node == n) {
        o0 = make_int4(0, 0, 0, 0);
        o1 = o0;
    } else {
        float dn = dinv[node];
        const float4* xp =
            reinterpret_cast<const float4*>(x + (size_t)node * 128 + q * 16);
        __half2 h[8];
#pragma unroll
        for (int j = 0; j < 4; ++j) {
            float4 a = xp[j];
            h[2 * j + 0] = __floats2half2_rn(a.x * dn, a.y * dn);
            h[2 * j + 1] = __floats2half2_rn(a.z * dn, a.w * dn);
        }
        o0 = reinterpret_cast<int4*>(h)[0];
        o1 = reinterpret_cast<int4*>(h)[1];
    }
    int4* op = reinterpret_cast<int4*>(xhT + ((size_t)q * (n + 1) + node) * 16);
    op[0] = o0;
    op[1] = o1;
}

// zero thT's dummy rows; run after mgemm1 (overlays aggT), before mgemm2
__global__ void zero_thT_k(__half* __restrict__ thT, int n) {
    int t = threadIdx.x;  // 64 threads
    int sl = t >> 4, j = t & 15;
    thT[((size_t)sl * (n + 1) + n) * 16 + j] = __float2half(0.0f);
}

// ---------------- sliced gathers, 8 nodes x 8 lanes per wave ----------------
// Payload: [slice][N+1][16] fp16 -> 32 B per node per slice; row N is zeros.
// Nodes taken in chunk-locally degree-sorted perm order.

__global__ __launch_bounds__(NT) void gatherT128_k(
    const int* __restrict__ rowptr, const int* __restrict__ pdeg,
    const int* __restrict__ perm, const int* __restrict__ srcs,
    const float* __restrict__ dinv, const __half* __restrict__ xhT,
    __half2* __restrict__ aggT, int n) {
    const int slice = blockIdx.x & 7;
    const int chunk = blockIdx.x >> 3;
    const int lane  = threadIdx.x & 63;
    const int wid   = threadIdx.x >> 6;
    const int g     = lane >> 3;   // node sub-group 0..7
    const int c     = lane & 7;    // half2 col within slice / srcs sub-index
    const int idx   = chunk * 32 + wid * 8 + g;
    if (idx >= n) return;  // shfl sources stay within each 8-lane group
    const int node = perm[idx];   // within idx's own 32-chunk

    const int e0 = rowptr[node];
    const int pd = pdeg[node];
    const char* base = (const char*)(xhT + (size_t)slice * (n + 1) * 16);
    const unsigned c4 = (unsigned)c * 4u;
    const h2 b10 = {(_Float16)1.0f, (_Float16)0.0f};
    const h2 b01 = {(_Float16)0.0f, (_Float16)1.0f};

    // self-loop
    h2 fs = *(const h2*)(base + (size_t)node * 32 + c4);
    float ax = dot2f(fs, b10, 0.0f);
    float ay = dot2f(fs, b01, 0.0f);

    int sidx = srcs[e0 + c];
    for (int jb = 0; jb < pd; jb += 8) {
        int snext = srcs[e0 + jb + 8 + c];  // unconditional: buffer padded
#pragma unroll
        for (int u = 0; u < 8; ++u) {
            int s = __shfl(sidx, (g << 3) | u, 64);
            h2 f = *(const h2*)(base + (unsigned)s * 32u + c4);
            ax = dot2f(f, b10, ax);
            ay = dot2f(f, b01, ay);
        }
        sidx = snext;
    }

    float dn = dinv[node];
    aggT[((size_t)slice * n + node) * 8 + c] = __floats2half2_rn(ax * dn, ay * dn);
}

// gatherT64: 4 slices of 16 cols; q8 -> (slice = q8>>1, node-half = q8&1).
// Writes row-major fp32 out directly (+b2): slice = one 64B line per row.
__global__ __launch_bounds__(NT) void gatherT64_k(
    const int* __restrict__ rowptr, const int* __restrict__ pdeg,
    const int* __restrict__ perm, const int* __restrict__ srcs,
    const float* __restrict__ dinv, const __half* __restrict__ thT,
    const float* __restrict__ b2, float* __restrict__ out, int n) {
    const int q8    = blockIdx.x & 7;
    const int slice = q8 >> 1;
    const int chunk = blockIdx.x >> 3;
    const int lane  = threadIdx.x & 63;
    const int wid   = threadIdx.x >> 6;
    const int g     = lane >> 3;
    const int c     = lane & 7;
    const int idx   = chunk * 64 + (q8 & 1) * 32 + wid * 8 + g;
    if (idx >= n) return;
    const int node = perm[idx];   // (chunk*64 + half*32) is 32-aligned

    const int e0 = rowptr[node];
    const int pd = pdeg[node];
    const char* base = (const char*)(thT + (size_t)slice * (n + 1) * 16);
    const unsigned c4 = (unsigned)c * 4u;
    const h2 b10 = {(_Float16)1.0f, (_Float16)0.0f};
    const h2 b01 = {(_Float16)0.0f, (_Float16)1.0f};

    h2 fs = *(const h2*)(base + (size_t)node * 32 + c4);
    float ax = dot2f(fs, b10, 0.0f);
    float ay = dot2f(fs, b01, 0.0f);

    int sidx = srcs[e0 + c];
    for (int jb = 0; jb < pd; jb += 8) {
        int snext = srcs[e0 + jb + 8 + c];
#pragma unroll
        for (int u = 0; u < 8; ++u) {
            int s = __shfl(sidx, (g << 3) | u, 64);
            h2 f = *(const h2*)(base + (unsigned)s * 32u + c4);
            ax = dot2f(f, b10, ax);
            ay = dot2f(f, b01, ay);
        }
        sidx = snext;
    }

    float dn = dinv[node];
    int col = slice * 16 + c * 2;
    *reinterpret_cast<float2*>(&out[(size_t)node * 64 + col]) =
        make_float2(ax * dn + b2[col], ay * dn + b2[col + 1]);
}

// ---------------- MFMA fp16 GEMM, register-resident B ----------------
// TIN=true : A is slice-major [8][nrows][16] fp16 (aggT, stride nrows).
// TOUT=true: out slice-major [OC/16][orows][16] fp16 (thT, stride orows).
template <int OC, bool RELU, bool BIAS, bool SCALE_DINV, bool TIN, bool TOUT>
__global__ __launch_bounds__(NT) void mgemm_k(
    const __half* __restrict__ A, const float* __restrict__ W,
    const float* __restrict__ bias, const float* __restrict__ dinv,
    __half* __restrict__ out, int nrows, int orows) {
    constexpr int NREP = OC / 64;  // 2 for OC=128, 1 for OC=64

    const int wid  = threadIdx.x >> 6;
    const int lane = threadIdx.x & 63;
    const int lrow = lane & 15;
    const int kgrp = lane >> 4;
    const int nbase = wid * 16 * NREP;

    // B fragments (loaded once, stay in VGPRs)
    half8 bf[NREP][4];
    float bv[NREP];
#pragma unroll
    for (int nt = 0; nt < NREP; ++nt) {
        int col = nbase + nt * 16 + lrow;
#pragma unroll
        for (int kk = 0; kk < 4; ++kk) {
#pragma unroll
            for (int j = 0; j < 8; ++j) {
                int k = kk * 32 + kgrp * 8 + j;
                bf[nt][kk][j] = (_Float16)W[(size_t)k * OC + col];
            }
        }
        bv[nt] = BIAS ? bias[col] : 0.0f;
    }

    const int m0 = blockIdx.x * 64;

    floatx4 acc[4][NREP];
#pragma unroll
    for (int mt = 0; mt < 4; ++mt)
#pragma unroll
        for (int nt = 0; nt < NREP; ++nt)
            acc[mt][nt] = floatx4{0.f, 0.f, 0.f, 0.f};

#pragma unroll
    for (int kk = 0; kk < 4; ++kk) {
        const int k0 = kk * 32 + kgrp * 8;
        half8 af[4];
#pragma unroll
        for (int mt = 0; mt < 4; ++mt) {
            int row = m0 + mt * 16 + lrow;
            if (row >= nrows) row = nrows - 1;  // clamp; stores guarded
            af[mt] = TIN
                ? *reinterpret_cast<const half8*>(
                      &A[(((size_t)(k0 >> 4)) * nrows + row) * 16 + (k0 & 15)])
                : *reinterpret_cast<const half8*>(&A[(size_t)row * 128 + k0]);
        }
#pragma unroll
        for (int mt = 0; mt < 4; ++mt)
#pragma unroll
            for (int nt = 0; nt < NREP; ++nt)
                acc[mt][nt] = __builtin_amdgcn_mfma_f32_16x16x32_f16(
                    af[mt], bf[nt][kk], acc[mt][nt], 0, 0, 0);
    }

#pragma unroll
    for (int mt = 0; mt < 4; ++mt) {
#pragma unroll
        for (int r = 0; r < 4; ++r) {
            int row = m0 + mt * 16 + kgrp * 4 + r;
            if (row < nrows) {
                float dn = SCALE_DINV ? dinv[row] : 1.0f;
#pragma unroll
                for (int nt = 0; nt < NREP; ++nt) {
                    float v = acc[mt][nt][r];
                    if (BIAS) v += bv[nt];
                    if (RELU) v = fmaxf(v, 0.0f);
                    if (SCALE_DINV) v *= dn;
                    int col = nbase + nt * 16 + lrow;
                    if (TOUT)
                        out[((size_t)(col >> 4) * orows + row) * 16 + (col & 15)] =
                            __float2half(v);
                    else
                        out[(size_t)row * OC + col] = __float2half(v);
                }
            }
        }
    }
}

// ---------------------------------------------------------------------------

extern "C" void kernel_launch(void* const* d_in, const int* in_sizes, int n_in,
                              void* d_out, int out_size, void* d_ws, size_t ws_size,
                              hipStream_t stream) {
    const float* x   = (const float*)d_in[0];
    const int*   ei  = (const int*)d_in[1];
    const float* W1  = (const float*)d_in[2];
    const float* b1  = (const float*)d_in[3];
    const float* W2  = (const float*)d_in[4];
    const float* b2  = (const float*)d_in[5];
    float*       out = (float*)d_out;

    const int N = in_sizes[0] / 128;
    const int E = in_sizes[1] / 2;
    const int* srcp = ei;      // edge_index[0]
    const int* dstp = ei + E;  // edge_index[1]

    const int nb   = (N + NT - 1) / NT;
    const int EPAD = E + 8 * N;  // >= sum(padded degrees) + prefetch slack

    // workspace (512B-aligned):
    //   dinv[N] | cnt[N] | pdeg[N] | rowptr[N] | bsum[nb] | perm[N] | srcs[EPAD]
    //   | regA: xhT[8][N+1][16] fp16, then h1[N][128] fp16
    //   | regB: aggT[8][N][16] fp16, then thT[4][N+1][16] fp16
    char* ws = (char*)d_ws;
    size_t off = 0;
    auto alloc = [&](size_t bytes) {
        char* p = ws + off;
        off = (off + bytes + 511) & ~(size_t)511;
        return p;
    };
    float*  dinv   = (float*)alloc((size_t)N * 4);
    int*    cnt    = (int*)alloc((size_t)N * 4);   // counts, then scatter cursor
    int*    pdeg   = (int*)alloc((size_t)N * 4);
    int*    rowptr = (int*)alloc((size_t)N * 4);
    int*    bsum   = (int*)alloc((size_t)nb * 4);
    int*    perm   = (int*)alloc((size_t)N * 4);
    int*    srcs   = (int*)alloc((size_t)EPAD * 4);
    __half* regA   = (__half*)alloc((size_t)(N + 1) * 128 * 2);
    __half* regB   = (__half*)alloc((size_t)(N + 1) * 128 * 2);

    // ---- padded CSR build + norm + within-chunk degree sort ----
    const int mi = (EPAD > N) ? EPAD : N;
    init_k<<<(mi + NT - 1) / NT, NT, 0, stream>>>(cnt, srcs, N, EPAD);
    deg_count_k<<<(E + NT - 1) / NT, NT, 0, stream>>>(dstp, cnt, E);
    scan1_k<<<nb, NT, 0, stream>>>(cnt, rowptr, bsum, dinv, pdeg, N);
    csort_k<<<nb, NT, 0, stream>>>(pdeg, perm, N);
    scan2_k<<<1, 512, 0, stream>>>(bsum, nb);
    scan3_k<<<nb, NT, 0, stream>>>(rowptr, bsum, cnt, N);
    {
        const int CH  = 2048;
        const int csz = (E + CH - 1) / CH;
        const int rpx = (N + 7) / 8;
        scatter_xcd_k<<<8 * CH, NT, 0, stream>>>(srcp, dstp, cnt, srcs, E, rpx, csz);
    }

    // ---- layer 1: xhT (padded, dummy row zeroed) -> aggT -> h1 ----
    conv1T_k<<<((N + 1) * 8 + NT - 1) / NT, NT, 0, stream>>>(x, dinv, regA, N);
    gatherT128_k<<<((N + 31) / 32) * 8, NT, 0, stream>>>(
        rowptr, pdeg, perm, srcs, dinv, regA, (__half2*)regB, N);
    __half* h1 = regA;  // overlays xhT (dead)
    mgemm_k<128, true, true, false, true, false><<<(N + 63) / 64, NT, 0, stream>>>(
        regB, W1, b1, nullptr, h1, N, N);

    // ---- layer 2: thT = (h1 @ W2)*dinv (slice-major, padded) -> out ----
    __half* thT = regB;  // overlays aggT (dead)
    zero_thT_k<<<1, 64, 0, stream>>>(thT, N);
    mgemm_k<64, false, false, true, false, true><<<(N + 63) / 64, NT, 0, stream>>>(
        h1, W2, nullptr, dinv, thT, N, N + 1);
    gatherT64_k<<<((N + 63) / 64) * 8, NT, 0, stream>>>(
        rowptr, pdeg, perm, srcs, dinv, thT, b2, out, N);
}